// Round 2
// baseline (806.515 us; speedup 1.0000x reference)
//
#include <hip/hip_runtime.h>

typedef unsigned short u16;
typedef unsigned int   u32;
typedef __bf16 bf16_t;
typedef bf16_t bf16x8 __attribute__((ext_vector_type(8)));
typedef float  f32x4  __attribute__((ext_vector_type(4)));

__device__ __forceinline__ float b2f(u16 u) {
  union { float f; u32 i; } v; v.i = ((u32)u) << 16; return v.f;
}
__device__ __forceinline__ u16 f2b(float f) {
  union { float f; u32 i; } v; v.f = f;
  u32 r = v.i + 0x7FFFu + ((v.i >> 16) & 1u);
  return (u16)(r >> 16);
}
__device__ __forceinline__ void ld4(const float* p, float* o) {
  const float4 v = *(const float4*)p; o[0]=v.x; o[1]=v.y; o[2]=v.z; o[3]=v.w;
}
__device__ __forceinline__ void ld4(const u16* p, float* o) {
  union { ushort4 v; u16 e[4]; } u; u.v = *(const ushort4*)p;
#pragma unroll
  for (int k = 0; k < 4; ++k) o[k] = b2f(u.e[k]);
}

// ---------------------------------------------------------------------------
// Prep kernels
// ---------------------------------------------------------------------------
__global__ void conv_w(const float* __restrict__ src, u16* __restrict__ dst, int n) {
  const int i = blockIdx.x * 256 + threadIdx.x;
  if (i < n) dst[i] = f2b(src[i]);
}

__global__ void prep_w2(const float* __restrict__ proj_w, const float* __restrict__ out_w,
                        u16* __restrict__ W2) {
  const int o = blockIdx.x, c = threadIdx.x;
  float acc = 0.f;
  for (int m = 0; m < 256; ++m)
    acc += proj_w[o*256 + m] * out_w[m*256 + c];
  W2[o*256 + c] = f2b(acc);
}

__global__ void prep_b2(const float* __restrict__ proj_w, const float* __restrict__ out_b,
                        const float* __restrict__ proj_b, float* __restrict__ b2v) {
  const int o = threadIdx.x;
  float acc = proj_b[o];
  for (int m = 0; m < 256; ++m) acc += proj_w[o*256 + m] * out_b[m];
  b2v[o] = acc;
}

// ---------------------------------------------------------------------------
// LN1 over C + shifted window partition.
// ---------------------------------------------------------------------------
__global__ __launch_bounds__(256, 2)
void ln1_kernel(const float* __restrict__ x, const float* __restrict__ g,
                const float* __restrict__ bb, u16* __restrict__ xn_tok,
                u16* __restrict__ x_tok) {
  const int bx = blockIdx.x;                 // 128: h*2 + half
  const int h = bx >> 1, w0 = (bx & 1) << 5;
  const int b = blockIdx.y;
  const int tid = threadIdx.x;
  __shared__ float X[256][33];
  __shared__ float ps[8][32], pq[8][32];
  __shared__ float mu_s[32], rs_s[32];
  const int w = tid & 31, cg = tid >> 5;
  float sum = 0.f, sq = 0.f;
  const float* xb = x + ((size_t)b * 256) * 4096 + h * 64 + w0;
  for (int i = 0; i < 32; ++i) {
    const int c = i*8 + cg;
    const float v = xb[(size_t)c * 4096 + w];
    X[c][w] = v; sum += v; sq += v*v;
  }
  ps[cg][w] = sum; pq[cg][w] = sq;
  __syncthreads();
  if (tid < 32) {
    float s = 0.f, q2 = 0.f;
#pragma unroll
    for (int j = 0; j < 8; ++j) { s += ps[j][tid]; q2 += pq[j][tid]; }
    const float mu = s * (1.f/256.f);
    mu_s[tid] = mu;
    rs_s[tid] = rsqrtf(fmaxf(q2 * (1.f/256.f) - mu*mu, 0.f) + 1e-6f);
  }
  __syncthreads();
  const int c = tid;
  const float gc = g[c], bc = bb[c];
  const int hp = (h + 60) & 63;              // h' = (h-4) mod 64
  const int wi = hp >> 3, tr = hp & 7;
  const int tokb = (b << 6) + (wi << 3);
  for (int w2 = 0; w2 < 32; ++w2) {
    const int wp = (w0 + w2 + 60) & 63;
    const int tok = (tokb + (wp >> 3)) * 64 + tr*8 + (wp & 7);
    const float v = X[c][w2];
    xn_tok[(size_t)tok * 256 + c] = f2b((v - mu_s[w2]) * rs_s[w2] * gc + bc);
    x_tok [(size_t)tok * 256 + c] = f2b(v);
  }
}

// ---------------------------------------------------------------------------
// MFMA GEMM: C = epi(A @ W^T + bias [+ res]).
// 128x128 tile, BK=64, XOR-swizzled LDS, XCD remap, LDS-transpose epilogue.
// EPI_BIAS: bias only. EPI_GELU: gelu(v+bias). EPI_RES: v+bias+res.
// ---------------------------------------------------------------------------
constexpr int EPI_BIAS = 0, EPI_GELU = 1, EPI_RES = 2;

template<int N, int K, int NB, int EPI, typename OutT, typename ResT>
__global__ __launch_bounds__(256, 2)
void gemm_bt(const u16* __restrict__ A, const u16* __restrict__ W,
             const float* __restrict__ bias, const ResT* __restrict__ res,
             OutT* __restrict__ C) {
  __shared__ u16 SMEM[2*128*64];
  u16* As = SMEM;
  u16* Ws = SMEM + 128*64;
  const int tid = threadIdx.x;
  const int lane = tid & 63;
  const int wave = tid >> 6;
  const int wm = (wave >> 1) << 6;
  const int wn = (wave & 1) << 6;
  const int id = blockIdx.x;
  const int kk = id >> 3, xx = id & 7;
  const int bn = kk % NB;
  const int bm = (kk / NB) * 8 + xx;
  const u16* Ab = A + (size_t)bm * 128 * K;
  const u16* Wb = W + (size_t)bn * 128 * K;
  f32x4 acc[4][4] = {};

  for (int kb = 0; kb < K; kb += 64) {
    uint4 av[4], wv4[4];
#pragma unroll
    for (int e = 0; e < 4; ++e) {
      const int f = e*256 + tid;
      const int r = f >> 3, c = f & 7;
      av[e]  = *(const uint4*)(Ab + (size_t)r*K + kb + c*8);
      wv4[e] = *(const uint4*)(Wb + (size_t)r*K + kb + c*8);
    }
    __syncthreads();
#pragma unroll
    for (int e = 0; e < 4; ++e) {
      const int f = e*256 + tid;
      const int r = f >> 3, c = f & 7;
      const int p = c ^ (r & 7);
      *(uint4*)(As + r*64 + p*8) = av[e];
      *(uint4*)(Ws + r*64 + p*8) = wv4[e];
    }
    __syncthreads();
#pragma unroll
    for (int ks = 0; ks < 2; ++ks) {
      bf16x8 af[4], wf[4];
#pragma unroll
      for (int i = 0; i < 4; ++i) {
        const int ra = wm + i*16 + (lane & 15);
        const int pa = ((ks<<2) + (lane >> 4)) ^ (ra & 7);
        af[i] = *(const bf16x8*)(As + ra*64 + pa*8);
        const int rb = wn + i*16 + (lane & 15);
        const int pb = ((ks<<2) + (lane >> 4)) ^ (rb & 7);
        wf[i] = *(const bf16x8*)(Ws + rb*64 + pb*8);
      }
#pragma unroll
      for (int i = 0; i < 4; ++i)
#pragma unroll
        for (int j = 0; j < 4; ++j)
          acc[i][j] = __builtin_amdgcn_mfma_f32_16x16x32_bf16(af[i], wf[j], acc[i][j], 0, 0, 0);
    }
  }
  __syncthreads();
  float* Es = (float*)SMEM + wave * (16*68);
  const int c0 = lane & 15, g4 = lane >> 4;
  float bj[4];
#pragma unroll
  for (int j = 0; j < 4; ++j) bj[j] = bias[bn*128 + wn + j*16 + c0];
#pragma unroll
  for (int i = 0; i < 4; ++i) {
#pragma unroll
    for (int j = 0; j < 4; ++j)
#pragma unroll
      for (int r = 0; r < 4; ++r) {
        float v = acc[i][j][r] + bj[j];
        Es[(g4*4 + r)*68 + j*16 + c0] = v;
      }
#pragma unroll
    for (int t = 0; t < 2; ++t) {
      const int r16 = t*8 + (lane >> 3);
      const int cc = (lane & 7) * 8;
      const float* ep = Es + r16*68 + cc;
      float v[8];
#pragma unroll
      for (int k = 0; k < 8; ++k) v[k] = ep[k];
      const int row = bm*128 + wm + i*16 + r16;
      const int colg = bn*128 + wn + cc;
      if constexpr (EPI == EPI_GELU) {
#pragma unroll
        for (int k = 0; k < 8; ++k)
          v[k] = 0.5f * v[k] * (1.f + erff(v[k] * 0.7071067811865475f));
      }
      if constexpr (EPI == EPI_RES) {
        float rv[8];
        ld4(res + (size_t)row * N + colg, rv);
        ld4(res + (size_t)row * N + colg + 4, rv + 4);
#pragma unroll
        for (int k = 0; k < 8; ++k) v[k] += rv[k];
      }
      if constexpr (sizeof(OutT) == 2) {
        union { uint4 q; u16 e[8]; } ov;
#pragma unroll
        for (int k = 0; k < 8; ++k) ov.e[k] = f2b(v[k]);
        *(uint4*)((u16*)C + (size_t)row * N + colg) = ov.q;
      } else {
        float4 o0 = {v[0],v[1],v[2],v[3]}, o1 = {v[4],v[5],v[6],v[7]};
        float* cp = (float*)C + (size_t)row * N + colg;
        *(float4*)cp = o0; *(float4*)(cp + 4) = o1;
      }
    }
  }
}

// ---------------------------------------------------------------------------
// Attention: one block per (window, head).
// ---------------------------------------------------------------------------
__global__ __launch_bounds__(256, 2)
void attn_kernel(const u16* __restrict__ qkv, u16* __restrict__ attn) {
  const int h = blockIdx.x;
  const int n = blockIdx.y;
  const int tid = threadIdx.x;
  const int lane = tid & 63, wv = tid >> 6;
  __shared__ u16 Qs[64*40];
  __shared__ u16 Ks[64*40];
  __shared__ u16 Vt[32*72];
  __shared__ u16 Ps[64*72];
  {
    const int row = tid >> 2, ch = tid & 3;
    const u16* base = qkv + (size_t)(n*64 + row) * 768 + h*32 + ch*8;
    *(uint4*)(Qs + row*40 + ch*8) = *(const uint4*)(base);
    *(uint4*)(Ks + row*40 + ch*8) = *(const uint4*)(base + 256);
    union { uint4 v; u16 e[8]; } tmp;
    tmp.v = *(const uint4*)(base + 512);
#pragma unroll
    for (int j = 0; j < 8; ++j) Vt[(ch*8 + j)*72 + row] = tmp.e[j];
  }
  __syncthreads();
  const int mrow = (wv << 4) + (lane & 15);
  const int q4 = lane >> 4;
  f32x4 s[4];
  {
    bf16x8 qa = *(const bf16x8*)(Qs + mrow*40 + q4*8);
#pragma unroll
    for (int nt = 0; nt < 4; ++nt) {
      bf16x8 kb = *(const bf16x8*)(Ks + (nt*16 + (lane & 15))*40 + q4*8);
      f32x4 z = {0.f, 0.f, 0.f, 0.f};
      s[nt] = __builtin_amdgcn_mfma_f32_16x16x32_bf16(qa, kb, z, 0, 0, 0);
    }
  }
  float pr[4][4];
#pragma unroll
  for (int r = 0; r < 4; ++r) {
    float m0 = fmaxf(fmaxf(s[0][r], s[1][r]), fmaxf(s[2][r], s[3][r]));
    m0 = fmaxf(m0, __shfl_xor(m0, 1, 64));
    m0 = fmaxf(m0, __shfl_xor(m0, 2, 64));
    m0 = fmaxf(m0, __shfl_xor(m0, 4, 64));
    m0 = fmaxf(m0, __shfl_xor(m0, 8, 64));
    const float cs = 0.25500526571944696f;  // log2(e)/sqrt(32)
    float p0 = exp2f(fminf((s[0][r] - m0) * cs, 0.f));
    float p1 = exp2f(fminf((s[1][r] - m0) * cs, 0.f));
    float p2 = exp2f(fminf((s[2][r] - m0) * cs, 0.f));
    float p3 = exp2f(fminf((s[3][r] - m0) * cs, 0.f));
    float sum = p0 + p1 + p2 + p3;
    sum += __shfl_xor(sum, 1, 64);
    sum += __shfl_xor(sum, 2, 64);
    sum += __shfl_xor(sum, 4, 64);
    sum += __shfl_xor(sum, 8, 64);
    const float inv = 1.f / sum;
    pr[0][r] = p0*inv; pr[1][r] = p1*inv; pr[2][r] = p2*inv; pr[3][r] = p3*inv;
  }
  {
    const int c = lane & 15;
#pragma unroll
    for (int nt = 0; nt < 4; ++nt)
#pragma unroll
      for (int r = 0; r < 4; ++r)
        Ps[((wv<<4) + (q4<<2) + r)*72 + nt*16 + c] = f2b(pr[nt][r]);
  }
  __syncthreads();
  f32x4 o0 = {0.f,0.f,0.f,0.f}, o1 = {0.f,0.f,0.f,0.f};
#pragma unroll
  for (int ks = 0; ks < 2; ++ks) {
    bf16x8 pa = *(const bf16x8*)(Ps + mrow*72 + ks*32 + q4*8);
    bf16x8 v0 = *(const bf16x8*)(Vt + (lane & 15)*72 + ks*32 + q4*8);
    bf16x8 v1 = *(const bf16x8*)(Vt + (16 + (lane & 15))*72 + ks*32 + q4*8);
    o0 = __builtin_amdgcn_mfma_f32_16x16x32_bf16(pa, v0, o0, 0, 0, 0);
    o1 = __builtin_amdgcn_mfma_f32_16x16x32_bf16(pa, v1, o1, 0, 0, 0);
  }
  {
    u16* Os = Qs + wv * 640;
    const int c = lane & 15;
#pragma unroll
    for (int r = 0; r < 4; ++r) {
      Os[((q4<<2) + r)*40 + c]      = f2b(o0[r]);
      Os[((q4<<2) + r)*40 + 16 + c] = f2b(o1[r]);
    }
    const int rr = lane >> 2, d0 = (lane & 3) * 8;
    union { uint4 q; u16 e[8]; } ov;
#pragma unroll
    for (int k = 0; k < 8; ++k) ov.e[k] = Os[rr*40 + d0 + k];
    *(uint4*)(attn + (size_t)(n*64 + (wv<<4) + rr) * 256 + h*32 + d0) = ov.q;
  }
}

// ---------------------------------------------------------------------------
// LN2: one wave per token. y (f32|bf16) -> zn bf16.
// ---------------------------------------------------------------------------
template<typename YT>
__global__ __launch_bounds__(256, 4)
void ln2_kernel(const YT* __restrict__ y, const float* __restrict__ g,
                const float* __restrict__ bb, u16* __restrict__ zn) {
  const int t = blockIdx.x * 4 + (threadIdx.x >> 6);
  const int lane = threadIdx.x & 63;
  float f[4];
  ld4(y + (size_t)t*256 + lane*4, f);
  float sum = f[0]+f[1]+f[2]+f[3];
  float sq  = f[0]*f[0]+f[1]*f[1]+f[2]*f[2]+f[3]*f[3];
#pragma unroll
  for (int d = 32; d; d >>= 1) { sum += __shfl_xor(sum, d, 64); sq += __shfl_xor(sq, d, 64); }
  const float mu = sum * (1.f/256.f);
  const float rs = rsqrtf(fmaxf(sq * (1.f/256.f) - mu*mu, 0.f) + 1e-6f);
  const float4 gv = *(const float4*)(g + lane*4);
  const float4 bv = *(const float4*)(bb + lane*4);
  union { ushort4 v; u16 e[4]; } ov;
  ov.e[0] = f2b((f[0]-mu)*rs*gv.x + bv.x);
  ov.e[1] = f2b((f[1]-mu)*rs*gv.y + bv.y);
  ov.e[2] = f2b((f[2]-mu)*rs*gv.z + bv.z);
  ov.e[3] = f2b((f[3]-mu)*rs*gv.w + bv.w);
  *(ushort4*)(zn + (size_t)t*256 + lane*4) = ov.v;
}

// ---------------------------------------------------------------------------
// Scatter: z (token layout, f32) -> out (image layout) with window reverse +
// shift. Block = one (b, h) output row-plane: reads 64 token rows (coalesced
// float4), LDS-transposes, writes 256 channel-rows of 64 w as full 256B
// lines.
// ---------------------------------------------------------------------------
__global__ __launch_bounds__(256, 2)
void scatter_kernel(const float* __restrict__ z, float* __restrict__ out) {
  __shared__ float T[64 * 260];            // T[w][c], pad 260 (float4-aligned)
  const int bx = blockIdx.x;               // b*64 + h
  const int b = bx >> 6, h = bx & 63;
  const int tid = threadIdx.x;
  const int hp = (h + 60) & 63;            // (h-4) mod 64
  const int wi = hp >> 3, tr = hp & 7;
  const int base = (b*64 + wi*8)*64 + tr*8;  // token index at (wj=0, tc=0)
  const int c0 = (tid & 63) * 4;
#pragma unroll
  for (int p = 0; p < 16; ++p) {
    const int r = p*4 + (tid >> 6);        // r = wj*8 + tc, 0..63
    const int t = base + (r >> 3)*64 + (r & 7);
    const float4 v = *(const float4*)(z + (size_t)t*256 + c0);
    *(float4*)(T + ((r + 4) & 63)*260 + c0) = v;   // w_img = (r+4) & 63
  }
  __syncthreads();
  float* ob = out + (size_t)b*1048576 + (size_t)h*64;
#pragma unroll
  for (int p = 0; p < 16; ++p) {
    const int c = p*16 + (tid >> 6)*4 + ((tid & 63) >> 4);
    const int w4 = (tid & 15) * 4;
    float4 v;
    v.x = T[(w4+0)*260 + c];
    v.y = T[(w4+1)*260 + c];
    v.z = T[(w4+2)*260 + c];
    v.w = T[(w4+3)*260 + c];
    *(float4*)(ob + (size_t)c*4096 + w4) = v;
  }
}

// ---------------------------------------------------------------------------
// Workspace layout (nA = 16 Mi elements = 32 MiB bf16 / 64 MiB f32):
//   [0,   2nA)  B   : xn -> attn-out -> zn (bf16)      live until 2nd fc1
//   [2nA, 8nA)  Cb  : qkv (bf16, dead after attn)
//        [2nA, 6nA)  H1 : h1 half (bf16, 64 MiB) overlays Cb head
//        [6nA,10nA)  Z  : z = y+z2 (f32, 64 MiB) overlays Cb tail + A
//   [8nA,10nA)  A   : x_tok (bf16, dead after gemm_proj)
//   [10nA, ..)  D   : y (f32 if yf32 else bf16)
//   then converted weights.
// ---------------------------------------------------------------------------
extern "C" void kernel_launch(void* const* d_in, const int* in_sizes, int n_in,
                              void* d_out, int out_size, void* d_ws, size_t ws_size,
                              hipStream_t stream) {
  const float* x       = (const float*)d_in[0];
  const float* norm1_g = (const float*)d_in[1];
  const float* norm1_b = (const float*)d_in[2];
  const float* in_w    = (const float*)d_in[3];
  const float* in_b    = (const float*)d_in[4];
  const float* out_w   = (const float*)d_in[5];
  const float* out_b   = (const float*)d_in[6];
  const float* proj_w  = (const float*)d_in[7];
  const float* proj_b  = (const float*)d_in[8];
  const float* norm2_g = (const float*)d_in[9];
  const float* norm2_b = (const float*)d_in[10];
  const float* fc1_w   = (const float*)d_in[11];
  const float* fc1_b   = (const float*)d_in[12];
  const float* fc2_w   = (const float*)d_in[13];
  const float* fc2_b   = (const float*)d_in[14];
  float* out = (float*)d_out;

  const size_t nA = 16777216;             // 65536 tokens x 256 ch
  const size_t nH = 8388608;              // tokens*ch per M-half

  char* base = (char*)d_ws;
  const bool yf32 = ws_size >= (14*nA + 1573888 + 1024);

  u16*   B  = (u16*)base;                 // xn -> attn-out -> zn
  u16*   Cb = (u16*)(base + nA*2);        // qkv
  u16*   H1 = (u16*)(base + nA*2);        // h1 half (bf16), overlays Cb
  float* Z  = (float*)(base + nA*6);      // z (f32), overlays Cb tail + A
  u16*   A  = (u16*)(base + nA*8);        // x_tok
  char*  Dp = base + nA*10;               // y
  char*  Wp = Dp + (yf32 ? nA*4 : nA*2);
  u16* W2    = (u16*)Wp;                  // 65536
  u16* inw_h = W2 + 65536;                // 196608
  u16* fc1_h = inw_h + 196608;            // 262144
  u16* fc2_h = fc1_h + 262144;            // 262144
  float* b2v = (float*)(fc2_h + 262144);  // 256

  conv_w<<<768, 256, 0, stream>>>(in_w, inw_h, 196608);
  conv_w<<<1024, 256, 0, stream>>>(fc1_w, fc1_h, 262144);
  conv_w<<<1024, 256, 0, stream>>>(fc2_w, fc2_h, 262144);
  prep_w2<<<256, 256, 0, stream>>>(proj_w, out_w, W2);
  prep_b2<<<1, 256, 0, stream>>>(proj_w, out_b, proj_b, b2v);

  ln1_kernel<<<dim3(128, 16), 256, 0, stream>>>(x, norm1_g, norm1_b, B, A);
  // qkv = xn @ in_w^T + in_b   (65536 x 768 x 256), NB=6
  gemm_bt<768, 256, 6, EPI_BIAS, u16, u16>
      <<<3072, 256, 0, stream>>>(B, inw_h, in_b, nullptr, Cb);
  attn_kernel<<<dim3(8, 1024), 256, 0, stream>>>(Cb, B);
  if (yf32) {
    float* D = (float*)Dp;
    gemm_bt<256, 256, 2, EPI_RES, float, u16>
        <<<1024, 256, 0, stream>>>(B, W2, b2v, A, D);
    ln2_kernel<float><<<16384, 256, 0, stream>>>(D, norm2_g, norm2_b, B);
    for (int mh = 0; mh < 2; ++mh) {
      // h1 = gelu(zn @ fc1^T + b1)   (32768 x 1024 x 256), NB=8
      gemm_bt<1024, 256, 8, EPI_GELU, u16, u16>
          <<<2048, 256, 0, stream>>>(B + mh*nH, fc1_h, fc1_b, nullptr, H1);
      // z = y + h1 @ fc2^T + b2      (32768 x 256 x 1024), NB=2
      gemm_bt<256, 1024, 2, EPI_RES, float, float>
          <<<512, 256, 0, stream>>>(H1, fc2_h, fc2_b, D + mh*nH, Z + mh*nH);
    }
  } else {
    u16* D = (u16*)Dp;
    gemm_bt<256, 256, 2, EPI_RES, u16, u16>
        <<<1024, 256, 0, stream>>>(B, W2, b2v, A, D);
    ln2_kernel<u16><<<16384, 256, 0, stream>>>(D, norm2_g, norm2_b, B);
    for (int mh = 0; mh < 2; ++mh) {
      gemm_bt<1024, 256, 8, EPI_GELU, u16, u16>
          <<<2048, 256, 0, stream>>>(B + mh*nH, fc1_h, fc1_b, nullptr, H1);
      gemm_bt<256, 1024, 2, EPI_RES, float, u16>
          <<<512, 256, 0, stream>>>(H1, fc2_h, fc2_b, (u16*)Dp + mh*nH, Z + mh*nH);
    }
  }
  scatter_kernel<<<1024, 256, 0, stream>>>(Z, out);
}

// Round 4
// 487.116 us; speedup vs baseline: 1.6557x; 1.6557x over previous
//
#include <hip/hip_runtime.h>

typedef unsigned short u16;
typedef unsigned int   u32;
typedef __bf16 bf16_t;
typedef bf16_t bf16x8 __attribute__((ext_vector_type(8)));
typedef float  f32x4  __attribute__((ext_vector_type(4)));

__device__ __forceinline__ float b2f(u16 u) {
  union { float f; u32 i; } v; v.i = ((u32)u) << 16; return v.f;
}
__device__ __forceinline__ u16 f2b(float f) {
  union { float f; u32 i; } v; v.f = f;
  u32 r = v.i + 0x7FFFu + ((v.i >> 16) & 1u);
  return (u16)(r >> 16);
}
__device__ __forceinline__ void ld4(const float* p, float* o) {
  const float4 v = *(const float4*)p; o[0]=v.x; o[1]=v.y; o[2]=v.z; o[3]=v.w;
}
__device__ __forceinline__ void ld4(const u16* p, float* o) {
  union { ushort4 v; u16 e[4]; } u; u.v = *(const ushort4*)p;
#pragma unroll
  for (int k = 0; k < 4; ++k) o[k] = b2f(u.e[k]);
}

// async global->LDS DMA, 16B per lane. LDS dest is wave-uniform base +
// lane*16; global src is per-lane.
__device__ __forceinline__ void gld16(const u16* g, u16* l) {
  __builtin_amdgcn_global_load_lds(
      (const __attribute__((address_space(1))) void*)g,
      (__attribute__((address_space(3))) void*)l, 16, 0, 0);
}

// ---------------------------------------------------------------------------
// Prep kernels
// ---------------------------------------------------------------------------
__global__ void conv_w(const float* __restrict__ src, u16* __restrict__ dst, int n) {
  const int i = blockIdx.x * 256 + threadIdx.x;
  if (i < n) dst[i] = f2b(src[i]);
}

__global__ void prep_w2(const float* __restrict__ proj_w, const float* __restrict__ out_w,
                        u16* __restrict__ W2) {
  const int o = blockIdx.x, c = threadIdx.x;
  float acc = 0.f;
  for (int m = 0; m < 256; ++m)
    acc += proj_w[o*256 + m] * out_w[m*256 + c];
  W2[o*256 + c] = f2b(acc);
}

__global__ void prep_b2(const float* __restrict__ proj_w, const float* __restrict__ out_b,
                        const float* __restrict__ proj_b, float* __restrict__ b2v) {
  const int o = threadIdx.x;
  float acc = proj_b[o];
  for (int m = 0; m < 256; ++m) acc += proj_w[o*256 + m] * out_b[m];
  b2v[o] = acc;
}

// ---------------------------------------------------------------------------
// LN1 over C + shifted window partition.
// ---------------------------------------------------------------------------
__global__ __launch_bounds__(256, 2)
void ln1_kernel(const float* __restrict__ x, const float* __restrict__ g,
                const float* __restrict__ bb, u16* __restrict__ xn_tok,
                u16* __restrict__ x_tok) {
  const int bx = blockIdx.x;                 // 128: h*2 + half
  const int h = bx >> 1, w0 = (bx & 1) << 5;
  const int b = blockIdx.y;
  const int tid = threadIdx.x;
  __shared__ float X[256][33];
  __shared__ float ps[8][32], pq[8][32];
  __shared__ float mu_s[32], rs_s[32];
  const int w = tid & 31, cg = tid >> 5;
  float sum = 0.f, sq = 0.f;
  const float* xb = x + ((size_t)b * 256) * 4096 + h * 64 + w0;
  for (int i = 0; i < 32; ++i) {
    const int c = i*8 + cg;
    const float v = xb[(size_t)c * 4096 + w];
    X[c][w] = v; sum += v; sq += v*v;
  }
  ps[cg][w] = sum; pq[cg][w] = sq;
  __syncthreads();
  if (tid < 32) {
    float s = 0.f, q2 = 0.f;
#pragma unroll
    for (int j = 0; j < 8; ++j) { s += ps[j][tid]; q2 += pq[j][tid]; }
    const float mu = s * (1.f/256.f);
    mu_s[tid] = mu;
    rs_s[tid] = rsqrtf(fmaxf(q2 * (1.f/256.f) - mu*mu, 0.f) + 1e-6f);
  }
  __syncthreads();
  const int c = tid;
  const float gc = g[c], bc = bb[c];
  const int hp = (h + 60) & 63;              // h' = (h-4) mod 64
  const int wi = hp >> 3, tr = hp & 7;
  const int tokb = (b << 6) + (wi << 3);
  for (int w2 = 0; w2 < 32; ++w2) {
    const int wp = (w0 + w2 + 60) & 63;
    const int tok = (tokb + (wp >> 3)) * 64 + tr*8 + (wp & 7);
    const float v = X[c][w2];
    xn_tok[(size_t)tok * 256 + c] = f2b((v - mu_s[w2]) * rs_s[w2] * gc + bc);
    x_tok [(size_t)tok * 256 + c] = f2b(v);
  }
}

// ---------------------------------------------------------------------------
// MFMA GEMM: C = epi(A @ W^T + bias [+ res]).
// 128x128 tile, BK=64, double-buffered LDS filled by global_load_lds with
// pre-swizzled per-lane source (LDS linear, XOR swizzle preserved on read).
// ONE barrier per K-chunk: stage(next) -> compute(cur) -> barrier (compiler
// emits vmcnt(0) drain before s_barrier, completing the staged DMA).
// ---------------------------------------------------------------------------
constexpr int EPI_BIAS = 0, EPI_GELU = 1, EPI_RES = 2;

template<int N, int K, int NB, int EPI, typename OutT, typename ResT>
__global__ __launch_bounds__(256, 2)
void gemm_bt(const u16* __restrict__ A, const u16* __restrict__ W,
             const float* __restrict__ bias, const ResT* __restrict__ res,
             OutT* __restrict__ C) {
  __shared__ u16 SMEM[4*128*64];           // 64 KB: [buf][A 8K | W 8K] u16
  const int tid = threadIdx.x;
  const int lane = tid & 63;
  const int wave = tid >> 6;
  const int wm = (wave >> 1) << 6;
  const int wn = (wave & 1) << 6;
  const int id = blockIdx.x;
  const int kk = id >> 3, xx = id & 7;
  const int bn = kk % NB;
  const int bm = (kk / NB) * 8 + xx;
  const u16* Ab = A + (size_t)bm * 128 * K;
  const u16* Wb = W + (size_t)bn * 128 * K;
  f32x4 acc[4][4] = {};

  // staging geometry: per wave 4 issues x 1KB; lane l covers LDS elements
  // (wave*4+e)*512 + l*8 = row r=(wave*4+e)*8 + l/8, slot p=l&7.
  // source col chunk = p ^ (r&7)  (so LDS[r][p] = G[r][p^(r&7)]).
  const int srl = lane >> 3;               // row-within-8
  const int sp  = lane & 7;                // slot
  auto stage = [&](int kb, int buf) {
    u16* As = SMEM + buf * 16384;
    u16* Ws = As + 8192;
#pragma unroll
    for (int e = 0; e < 4; ++e) {
      const int r = (wave*4 + e)*8 + srl;
      const int c = sp ^ (r & 7);
      const int lo = (wave*4 + e)*512;
      gld16(Ab + (size_t)r*K + kb + c*8, As + lo);
      gld16(Wb + (size_t)r*K + kb + c*8, Ws + lo);
    }
  };

  stage(0, 0);
  __syncthreads();                         // vmcnt(0) drain -> buf0 ready
  for (int kc = 0; kc < K/64; ++kc) {
    const int buf = kc & 1;
    if (kc*64 + 64 < K) stage(kc*64 + 64, buf ^ 1);
    const u16* As = SMEM + buf * 16384;
    const u16* Ws = As + 8192;
#pragma unroll
    for (int ks = 0; ks < 2; ++ks) {
      bf16x8 af[4], wf[4];
#pragma unroll
      for (int i = 0; i < 4; ++i) {
        const int ra = wm + i*16 + (lane & 15);
        const int pa = ((ks<<2) + (lane >> 4)) ^ (ra & 7);
        af[i] = *(const bf16x8*)(As + ra*64 + pa*8);
        const int rb = wn + i*16 + (lane & 15);
        const int pb = ((ks<<2) + (lane >> 4)) ^ (rb & 7);
        wf[i] = *(const bf16x8*)(Ws + rb*64 + pb*8);
      }
#pragma unroll
      for (int i = 0; i < 4; ++i)
#pragma unroll
        for (int j = 0; j < 4; ++j)
          acc[i][j] = __builtin_amdgcn_mfma_f32_16x16x32_bf16(af[i], wf[j], acc[i][j], 0, 0, 0);
    }
    __syncthreads();                       // next buf ready + WAR guard
  }
  float* Es = (float*)SMEM + wave * (16*68);
  const int c0 = lane & 15, g4 = lane >> 4;
  float bj[4];
#pragma unroll
  for (int j = 0; j < 4; ++j) bj[j] = bias[bn*128 + wn + j*16 + c0];
#pragma unroll
  for (int i = 0; i < 4; ++i) {
#pragma unroll
    for (int j = 0; j < 4; ++j)
#pragma unroll
      for (int r = 0; r < 4; ++r) {
        float v = acc[i][j][r] + bj[j];
        Es[(g4*4 + r)*68 + j*16 + c0] = v;
      }
#pragma unroll
    for (int t = 0; t < 2; ++t) {
      const int r16 = t*8 + (lane >> 3);
      const int cc = (lane & 7) * 8;
      const float* ep = Es + r16*68 + cc;
      float v[8];
#pragma unroll
      for (int k = 0; k < 8; ++k) v[k] = ep[k];
      const int row = bm*128 + wm + i*16 + r16;
      const int colg = bn*128 + wn + cc;
      if constexpr (EPI == EPI_GELU) {
#pragma unroll
        for (int k = 0; k < 8; ++k)
          v[k] = 0.5f * v[k] * (1.f + erff(v[k] * 0.7071067811865475f));
      }
      if constexpr (EPI == EPI_RES) {
        float rv[8];
        ld4(res + (size_t)row * N + colg, rv);
        ld4(res + (size_t)row * N + colg + 4, rv + 4);
#pragma unroll
        for (int k = 0; k < 8; ++k) v[k] += rv[k];
      }
      if constexpr (sizeof(OutT) == 2) {
        union { uint4 q; u16 e[8]; } ov;
#pragma unroll
        for (int k = 0; k < 8; ++k) ov.e[k] = f2b(v[k]);
        *(uint4*)((u16*)C + (size_t)row * N + colg) = ov.q;
      } else {
        float4 o0 = {v[0],v[1],v[2],v[3]}, o1 = {v[4],v[5],v[6],v[7]};
        float* cp = (float*)C + (size_t)row * N + colg;
        *(float4*)cp = o0; *(float4*)(cp + 4) = o1;
      }
    }
  }
}

// ---------------------------------------------------------------------------
// Attention: one block per (window, head).
// ---------------------------------------------------------------------------
__global__ __launch_bounds__(256, 2)
void attn_kernel(const u16* __restrict__ qkv, u16* __restrict__ attn) {
  const int h = blockIdx.x;
  const int n = blockIdx.y;
  const int tid = threadIdx.x;
  const int lane = tid & 63, wv = tid >> 6;
  __shared__ u16 Qs[64*40];
  __shared__ u16 Ks[64*40];
  __shared__ u16 Vt[32*72];
  __shared__ u16 Ps[64*72];
  {
    const int row = tid >> 2, ch = tid & 3;
    const u16* base = qkv + (size_t)(n*64 + row) * 768 + h*32 + ch*8;
    *(uint4*)(Qs + row*40 + ch*8) = *(const uint4*)(base);
    *(uint4*)(Ks + row*40 + ch*8) = *(const uint4*)(base + 256);
    union { uint4 v; u16 e[8]; } tmp;
    tmp.v = *(const uint4*)(base + 512);
#pragma unroll
    for (int j = 0; j < 8; ++j) Vt[(ch*8 + j)*72 + row] = tmp.e[j];
  }
  __syncthreads();
  const int mrow = (wv << 4) + (lane & 15);
  const int q4 = lane >> 4;
  f32x4 s[4];
  {
    bf16x8 qa = *(const bf16x8*)(Qs + mrow*40 + q4*8);
#pragma unroll
    for (int nt = 0; nt < 4; ++nt) {
      bf16x8 kb = *(const bf16x8*)(Ks + (nt*16 + (lane & 15))*40 + q4*8);
      f32x4 z = {0.f, 0.f, 0.f, 0.f};
      s[nt] = __builtin_amdgcn_mfma_f32_16x16x32_bf16(qa, kb, z, 0, 0, 0);
    }
  }
  float pr[4][4];
#pragma unroll
  for (int r = 0; r < 4; ++r) {
    float m0 = fmaxf(fmaxf(s[0][r], s[1][r]), fmaxf(s[2][r], s[3][r]));
    m0 = fmaxf(m0, __shfl_xor(m0, 1, 64));
    m0 = fmaxf(m0, __shfl_xor(m0, 2, 64));
    m0 = fmaxf(m0, __shfl_xor(m0, 4, 64));
    m0 = fmaxf(m0, __shfl_xor(m0, 8, 64));
    const float cs = 0.25500526571944696f;  // log2(e)/sqrt(32)
    float p0 = exp2f(fminf((s[0][r] - m0) * cs, 0.f));
    float p1 = exp2f(fminf((s[1][r] - m0) * cs, 0.f));
    float p2 = exp2f(fminf((s[2][r] - m0) * cs, 0.f));
    float p3 = exp2f(fminf((s[3][r] - m0) * cs, 0.f));
    float sum = p0 + p1 + p2 + p3;
    sum += __shfl_xor(sum, 1, 64);
    sum += __shfl_xor(sum, 2, 64);
    sum += __shfl_xor(sum, 4, 64);
    sum += __shfl_xor(sum, 8, 64);
    const float inv = 1.f / sum;
    pr[0][r] = p0*inv; pr[1][r] = p1*inv; pr[2][r] = p2*inv; pr[3][r] = p3*inv;
  }
  {
    const int c = lane & 15;
#pragma unroll
    for (int nt = 0; nt < 4; ++nt)
#pragma unroll
      for (int r = 0; r < 4; ++r)
        Ps[((wv<<4) + (q4<<2) + r)*72 + nt*16 + c] = f2b(pr[nt][r]);
  }
  __syncthreads();
  f32x4 o0 = {0.f,0.f,0.f,0.f}, o1 = {0.f,0.f,0.f,0.f};
#pragma unroll
  for (int ks = 0; ks < 2; ++ks) {
    bf16x8 pa = *(const bf16x8*)(Ps + mrow*72 + ks*32 + q4*8);
    bf16x8 v0 = *(const bf16x8*)(Vt + (lane & 15)*72 + ks*32 + q4*8);
    bf16x8 v1 = *(const bf16x8*)(Vt + (16 + (lane & 15))*72 + ks*32 + q4*8);
    o0 = __builtin_amdgcn_mfma_f32_16x16x32_bf16(pa, v0, o0, 0, 0, 0);
    o1 = __builtin_amdgcn_mfma_f32_16x16x32_bf16(pa, v1, o1, 0, 0, 0);
  }
  {
    u16* Os = Qs + wv * 640;
    const int c = lane & 15;
#pragma unroll
    for (int r = 0; r < 4; ++r) {
      Os[((q4<<2) + r)*40 + c]      = f2b(o0[r]);
      Os[((q4<<2) + r)*40 + 16 + c] = f2b(o1[r]);
    }
    const int rr = lane >> 2, d0 = (lane & 3) * 8;
    union { uint4 q; u16 e[8]; } ov;
#pragma unroll
    for (int k = 0; k < 8; ++k) ov.e[k] = Os[rr*40 + d0 + k];
    *(uint4*)(attn + (size_t)(n*64 + (wv<<4) + rr) * 256 + h*32 + d0) = ov.q;
  }
}

// ---------------------------------------------------------------------------
// LN2: one wave per token. y (f32|bf16) -> zn bf16.
// ---------------------------------------------------------------------------
template<typename YT>
__global__ __launch_bounds__(256, 4)
void ln2_kernel(const YT* __restrict__ y, const float* __restrict__ g,
                const float* __restrict__ bb, u16* __restrict__ zn) {
  const int t = blockIdx.x * 4 + (threadIdx.x >> 6);
  const int lane = threadIdx.x & 63;
  float f[4];
  ld4(y + (size_t)t*256 + lane*4, f);
  float sum = f[0]+f[1]+f[2]+f[3];
  float sq  = f[0]*f[0]+f[1]*f[1]+f[2]*f[2]+f[3]*f[3];
#pragma unroll
  for (int d = 32; d; d >>= 1) { sum += __shfl_xor(sum, d, 64); sq += __shfl_xor(sq, d, 64); }
  const float mu = sum * (1.f/256.f);
  const float rs = rsqrtf(fmaxf(sq * (1.f/256.f) - mu*mu, 0.f) + 1e-6f);
  const float4 gv = *(const float4*)(g + lane*4);
  const float4 bv = *(const float4*)(bb + lane*4);
  union { ushort4 v; u16 e[4]; } ov;
  ov.e[0] = f2b((f[0]-mu)*rs*gv.x + bv.x);
  ov.e[1] = f2b((f[1]-mu)*rs*gv.y + bv.y);
  ov.e[2] = f2b((f[2]-mu)*rs*gv.z + bv.z);
  ov.e[3] = f2b((f[3]-mu)*rs*gv.w + bv.w);
  *(ushort4*)(zn + (size_t)t*256 + lane*4) = ov.v;
}

// ---------------------------------------------------------------------------
// Scatter: z (token layout, f32) -> out (image layout) with window reverse +
// shift.
// ---------------------------------------------------------------------------
__global__ __launch_bounds__(256, 2)
void scatter_kernel(const float* __restrict__ z, float* __restrict__ out) {
  __shared__ float T[64 * 260];            // T[w][c], pad 260 (float4-aligned)
  const int bx = blockIdx.x;               // b*64 + h
  const int b = bx >> 6, h = bx & 63;
  const int tid = threadIdx.x;
  const int hp = (h + 60) & 63;            // (h-4) mod 64
  const int wi = hp >> 3, tr = hp & 7;
  const int base = (b*64 + wi*8)*64 + tr*8;  // token index at (wj=0, tc=0)
  const int c0 = (tid & 63) * 4;
#pragma unroll
  for (int p = 0; p < 16; ++p) {
    const int r = p*4 + (tid >> 6);        // r = wj*8 + tc, 0..63
    const int t = base + (r >> 3)*64 + (r & 7);
    const float4 v = *(const float4*)(z + (size_t)t*256 + c0);
    *(float4*)(T + ((r + 4) & 63)*260 + c0) = v;   // w_img = (r+4) & 63
  }
  __syncthreads();
  float* ob = out + (size_t)b*1048576 + (size_t)h*64;
#pragma unroll
  for (int p = 0; p < 16; ++p) {
    const int c = p*16 + (tid >> 6)*4 + ((tid & 63) >> 4);
    const int w4 = (tid & 15) * 4;
    float4 v;
    v.x = T[(w4+0)*260 + c];
    v.y = T[(w4+1)*260 + c];
    v.z = T[(w4+2)*260 + c];
    v.w = T[(w4+3)*260 + c];
    *(float4*)(ob + (size_t)c*4096 + w4) = v;
  }
}

// ---------------------------------------------------------------------------
// Workspace layout (nA = 16 Mi elements = 32 MiB bf16 / 64 MiB f32):
//   [0,   2nA)  B   : xn -> attn-out -> zn (bf16)      live until 2nd fc1
//   [2nA, 8nA)  Cb  : qkv (bf16, dead after attn)
//        [2nA, 6nA)  H1 : h1 half (bf16, 64 MiB) overlays Cb head
//        [6nA,10nA)  Z  : z = y+z2 (f32, 64 MiB) overlays Cb tail + A
//   [8nA,10nA)  A   : x_tok (bf16, dead after gemm_proj)
//   [10nA, ..)  D   : y (f32 if yf32 else bf16)
//   then converted weights.
// ---------------------------------------------------------------------------
extern "C" void kernel_launch(void* const* d_in, const int* in_sizes, int n_in,
                              void* d_out, int out_size, void* d_ws, size_t ws_size,
                              hipStream_t stream) {
  const float* x       = (const float*)d_in[0];
  const float* norm1_g = (const float*)d_in[1];
  const float* norm1_b = (const float*)d_in[2];
  const float* in_w    = (const float*)d_in[3];
  const float* in_b    = (const float*)d_in[4];
  const float* out_w   = (const float*)d_in[5];
  const float* out_b   = (const float*)d_in[6];
  const float* proj_w  = (const float*)d_in[7];
  const float* proj_b  = (const float*)d_in[8];
  const float* norm2_g = (const float*)d_in[9];
  const float* norm2_b = (const float*)d_in[10];
  const float* fc1_w   = (const float*)d_in[11];
  const float* fc1_b   = (const float*)d_in[12];
  const float* fc2_w   = (const float*)d_in[13];
  const float* fc2_b   = (const float*)d_in[14];
  float* out = (float*)d_out;

  const size_t nA = 16777216;             // 65536 tokens x 256 ch
  const size_t nH = 8388608;              // tokens*ch per M-half

  char* base = (char*)d_ws;
  const bool yf32 = ws_size >= (14*nA + 1573888 + 1024);

  u16*   B  = (u16*)base;                 // xn -> attn-out -> zn
  u16*   Cb = (u16*)(base + nA*2);        // qkv
  u16*   H1 = (u16*)(base + nA*2);        // h1 half (bf16), overlays Cb
  float* Z  = (float*)(base + nA*6);      // z (f32), overlays Cb tail + A
  u16*   A  = (u16*)(base + nA*8);        // x_tok
  char*  Dp = base + nA*10;               // y
  char*  Wp = Dp + (yf32 ? nA*4 : nA*2);
  u16* W2    = (u16*)Wp;                  // 65536
  u16* inw_h = W2 + 65536;                // 196608
  u16* fc1_h = inw_h + 196608;            // 262144
  u16* fc2_h = fc1_h + 262144;            // 262144
  float* b2v = (float*)(fc2_h + 262144);  // 256

  conv_w<<<768, 256, 0, stream>>>(in_w, inw_h, 196608);
  conv_w<<<1024, 256, 0, stream>>>(fc1_w, fc1_h, 262144);
  conv_w<<<1024, 256, 0, stream>>>(fc2_w, fc2_h, 262144);
  prep_w2<<<256, 256, 0, stream>>>(proj_w, out_w, W2);
  prep_b2<<<1, 256, 0, stream>>>(proj_w, out_b, proj_b, b2v);

  ln1_kernel<<<dim3(128, 16), 256, 0, stream>>>(x, norm1_g, norm1_b, B, A);
  // qkv = xn @ in_w^T + in_b   (65536 x 768 x 256), NB=6
  gemm_bt<768, 256, 6, EPI_BIAS, u16, u16>
      <<<3072, 256, 0, stream>>>(B, inw_h, in_b, nullptr, Cb);
  attn_kernel<<<dim3(8, 1024), 256, 0, stream>>>(Cb, B);
  if (yf32) {
    float* D = (float*)Dp;
    gemm_bt<256, 256, 2, EPI_RES, float, u16>
        <<<1024, 256, 0, stream>>>(B, W2, b2v, A, D);
    ln2_kernel<float><<<16384, 256, 0, stream>>>(D, norm2_g, norm2_b, B);
    for (int mh = 0; mh < 2; ++mh) {
      // h1 = gelu(zn @ fc1^T + b1)   (32768 x 1024 x 256), NB=8
      gemm_bt<1024, 256, 8, EPI_GELU, u16, u16>
          <<<2048, 256, 0, stream>>>(B + mh*nH, fc1_h, fc1_b, nullptr, H1);
      // z = y + h1 @ fc2^T + b2      (32768 x 256 x 1024), NB=2
      gemm_bt<256, 1024, 2, EPI_RES, float, float>
          <<<512, 256, 0, stream>>>(H1, fc2_h, fc2_b, D + mh*nH, Z + mh*nH);
    }
  } else {
    u16* D = (u16*)Dp;
    gemm_bt<256, 256, 2, EPI_RES, u16, u16>
        <<<1024, 256, 0, stream>>>(B, W2, b2v, A, D);
    ln2_kernel<u16><<<16384, 256, 0, stream>>>(D, norm2_g, norm2_b, B);
    for (int mh = 0; mh < 2; ++mh) {
      gemm_bt<1024, 256, 8, EPI_GELU, u16, u16>
          <<<2048, 256, 0, stream>>>(B + mh*nH, fc1_h, fc1_b, nullptr, H1);
      gemm_bt<256, 1024, 2, EPI_RES, float, u16>
          <<<512, 256, 0, stream>>>(H1, fc2_h, fc2_b, (u16*)Dp + mh*nH, Z + mh*nH);
    }
  }
  scatter_kernel<<<1024, 256, 0, stream>>>(Z, out);
}

// Round 5
// 459.659 us; speedup vs baseline: 1.7546x; 1.0597x over previous
//
#include <hip/hip_runtime.h>

typedef unsigned short u16;
typedef unsigned int   u32;
typedef __bf16 bf16_t;
typedef bf16_t bf16x8 __attribute__((ext_vector_type(8)));
typedef float  f32x4  __attribute__((ext_vector_type(4)));

__device__ __forceinline__ float b2f(u16 u) {
  union { float f; u32 i; } v; v.i = ((u32)u) << 16; return v.f;
}
__device__ __forceinline__ u16 f2b(float f) {
  union { float f; u32 i; } v; v.f = f;
  u32 r = v.i + 0x7FFFu + ((v.i >> 16) & 1u);
  return (u16)(r >> 16);
}
__device__ __forceinline__ void ld4(const float* p, float* o) {
  const float4 v = *(const float4*)p; o[0]=v.x; o[1]=v.y; o[2]=v.z; o[3]=v.w;
}
__device__ __forceinline__ void ld4(const u16* p, float* o) {
  union { ushort4 v; u16 e[4]; } u; u.v = *(const ushort4*)p;
#pragma unroll
  for (int k = 0; k < 4; ++k) o[k] = b2f(u.e[k]);
}

// async global->LDS DMA, 16B per lane. LDS dest is wave-uniform base +
// lane*16; global src is per-lane.
__device__ __forceinline__ void gld16(const u16* g, u16* l) {
  __builtin_amdgcn_global_load_lds(
      (const __attribute__((address_space(1))) void*)g,
      (__attribute__((address_space(3))) void*)l, 16, 0, 0);
}

// gelu(v) = 0.5 v (1 + erf(v/sqrt(2))), erf via Abramowitz-Stegun 7.1.26
// (|err| <= 1.5e-7, far below bf16 quantization of h1). Branchless:
// 1 rcp + 1 exp2 + ~13 fma vs libm erff's ~30-40 VALU ops.
__device__ __forceinline__ float fast_gelu(float v) {
  const float u = v * 0.7071067811865475f;
  const float s = fabsf(u);
  const float t = __builtin_amdgcn_rcpf(fmaf(0.3275911f, s, 1.f));
  const float poly = t*(0.254829592f + t*(-0.284496736f +
                     t*(1.421413741f + t*(-1.453152027f + t*1.061405429f))));
  const float E = exp2f(-s*s*1.4426950408889634f);
  const float q = poly * E;                   // = 1 - erf(s)
  const float phi = (u >= 0.f) ? (2.f - q) : q;  // 1 + erf(u)
  return 0.5f * v * phi;
}

// ---------------------------------------------------------------------------
// Prep kernels
// ---------------------------------------------------------------------------
__global__ void conv_w(const float* __restrict__ src, u16* __restrict__ dst, int n) {
  const int i = blockIdx.x * 256 + threadIdx.x;
  if (i < n) dst[i] = f2b(src[i]);
}

__global__ void prep_w2(const float* __restrict__ proj_w, const float* __restrict__ out_w,
                        u16* __restrict__ W2) {
  const int o = blockIdx.x, c = threadIdx.x;
  float acc = 0.f;
  for (int m = 0; m < 256; ++m)
    acc += proj_w[o*256 + m] * out_w[m*256 + c];
  W2[o*256 + c] = f2b(acc);
}

__global__ void prep_b2(const float* __restrict__ proj_w, const float* __restrict__ out_b,
                        const float* __restrict__ proj_b, float* __restrict__ b2v) {
  const int o = threadIdx.x;
  float acc = proj_b[o];
  for (int m = 0; m < 256; ++m) acc += proj_w[o*256 + m] * out_b[m];
  b2v[o] = acc;
}

// ---------------------------------------------------------------------------
// LN1 over C + shifted window partition.
// ---------------------------------------------------------------------------
__global__ __launch_bounds__(256, 2)
void ln1_kernel(const float* __restrict__ x, const float* __restrict__ g,
                const float* __restrict__ bb, u16* __restrict__ xn_tok,
                u16* __restrict__ x_tok) {
  const int bx = blockIdx.x;                 // 128: h*2 + half
  const int h = bx >> 1, w0 = (bx & 1) << 5;
  const int b = blockIdx.y;
  const int tid = threadIdx.x;
  __shared__ float X[256][33];
  __shared__ float ps[8][32], pq[8][32];
  __shared__ float mu_s[32], rs_s[32];
  const int w = tid & 31, cg = tid >> 5;
  float sum = 0.f, sq = 0.f;
  const float* xb = x + ((size_t)b * 256) * 4096 + h * 64 + w0;
  for (int i = 0; i < 32; ++i) {
    const int c = i*8 + cg;
    const float v = xb[(size_t)c * 4096 + w];
    X[c][w] = v; sum += v; sq += v*v;
  }
  ps[cg][w] = sum; pq[cg][w] = sq;
  __syncthreads();
  if (tid < 32) {
    float s = 0.f, q2 = 0.f;
#pragma unroll
    for (int j = 0; j < 8; ++j) { s += ps[j][tid]; q2 += pq[j][tid]; }
    const float mu = s * (1.f/256.f);
    mu_s[tid] = mu;
    rs_s[tid] = rsqrtf(fmaxf(q2 * (1.f/256.f) - mu*mu, 0.f) + 1e-6f);
  }
  __syncthreads();
  const int c = tid;
  const float gc = g[c], bc = bb[c];
  const int hp = (h + 60) & 63;              // h' = (h-4) mod 64
  const int wi = hp >> 3, tr = hp & 7;
  const int tokb = (b << 6) + (wi << 3);
  for (int w2 = 0; w2 < 32; ++w2) {
    const int wp = (w0 + w2 + 60) & 63;
    const int tok = (tokb + (wp >> 3)) * 64 + tr*8 + (wp & 7);
    const float v = X[c][w2];
    xn_tok[(size_t)tok * 256 + c] = f2b((v - mu_s[w2]) * rs_s[w2] * gc + bc);
    x_tok [(size_t)tok * 256 + c] = f2b(v);
  }
}

// ---------------------------------------------------------------------------
// MFMA GEMM: C = epi(A @ W^T + bias [+ res]).
// 128x128 tile, BK=64, double-buffered LDS filled by global_load_lds with
// pre-swizzled per-lane source (LDS linear, XOR swizzle preserved on read).
// ONE barrier per K-chunk: stage(next) -> compute(cur) -> barrier (compiler
// emits vmcnt(0) drain before s_barrier, completing the staged DMA).
// ---------------------------------------------------------------------------
constexpr int EPI_BIAS = 0, EPI_GELU = 1, EPI_RES = 2;

template<int N, int K, int NB, int EPI, typename OutT, typename ResT>
__global__ __launch_bounds__(256, 2)
void gemm_bt(const u16* __restrict__ A, const u16* __restrict__ W,
             const float* __restrict__ bias, const ResT* __restrict__ res,
             OutT* __restrict__ C) {
  __shared__ u16 SMEM[4*128*64];           // 64 KB: [buf][A 8K | W 8K] u16
  const int tid = threadIdx.x;
  const int lane = tid & 63;
  const int wave = tid >> 6;
  const int wm = (wave >> 1) << 6;
  const int wn = (wave & 1) << 6;
  const int id = blockIdx.x;
  const int kk = id >> 3, xx = id & 7;
  const int bn = kk % NB;
  const int bm = (kk / NB) * 8 + xx;
  const u16* Ab = A + (size_t)bm * 128 * K;
  const u16* Wb = W + (size_t)bn * 128 * K;
  f32x4 acc[4][4] = {};

  // staging geometry: per wave 4 issues x 1KB; lane l covers LDS elements
  // (wave*4+e)*512 + l*8 = row r=(wave*4+e)*8 + l/8, slot p=l&7.
  // source col chunk = p ^ (r&7)  (so LDS[r][p] = G[r][p^(r&7)]).
  const int srl = lane >> 3;               // row-within-8
  const int sp  = lane & 7;                // slot
  auto stage = [&](int kb, int buf) {
    u16* As = SMEM + buf * 16384;
    u16* Ws = As + 8192;
#pragma unroll
    for (int e = 0; e < 4; ++e) {
      const int r = (wave*4 + e)*8 + srl;
      const int c = sp ^ (r & 7);
      const int lo = (wave*4 + e)*512;
      gld16(Ab + (size_t)r*K + kb + c*8, As + lo);
      gld16(Wb + (size_t)r*K + kb + c*8, Ws + lo);
    }
  };

  stage(0, 0);
  __syncthreads();                         // vmcnt(0) drain -> buf0 ready
  for (int kc = 0; kc < K/64; ++kc) {
    const int buf = kc & 1;
    if (kc*64 + 64 < K) stage(kc*64 + 64, buf ^ 1);
    const u16* As = SMEM + buf * 16384;
    const u16* Ws = As + 8192;
#pragma unroll
    for (int ks = 0; ks < 2; ++ks) {
      bf16x8 af[4], wf[4];
#pragma unroll
      for (int i = 0; i < 4; ++i) {
        const int ra = wm + i*16 + (lane & 15);
        const int pa = ((ks<<2) + (lane >> 4)) ^ (ra & 7);
        af[i] = *(const bf16x8*)(As + ra*64 + pa*8);
        const int rb = wn + i*16 + (lane & 15);
        const int pb = ((ks<<2) + (lane >> 4)) ^ (rb & 7);
        wf[i] = *(const bf16x8*)(Ws + rb*64 + pb*8);
      }
#pragma unroll
      for (int i = 0; i < 4; ++i)
#pragma unroll
        for (int j = 0; j < 4; ++j)
          acc[i][j] = __builtin_amdgcn_mfma_f32_16x16x32_bf16(af[i], wf[j], acc[i][j], 0, 0, 0);
    }
    __syncthreads();                       // next buf ready + WAR guard
  }
  float* Es = (float*)SMEM + wave * (16*68);
  const int c0 = lane & 15, g4 = lane >> 4;
  float bj[4];
#pragma unroll
  for (int j = 0; j < 4; ++j) bj[j] = bias[bn*128 + wn + j*16 + c0];
#pragma unroll
  for (int i = 0; i < 4; ++i) {
#pragma unroll
    for (int j = 0; j < 4; ++j)
#pragma unroll
      for (int r = 0; r < 4; ++r) {
        float v = acc[i][j][r] + bj[j];
        if constexpr (EPI == EPI_GELU) v = fast_gelu(v);
        Es[(g4*4 + r)*68 + j*16 + c0] = v;
      }
#pragma unroll
    for (int t = 0; t < 2; ++t) {
      const int r16 = t*8 + (lane >> 3);
      const int cc = (lane & 7) * 8;
      const float* ep = Es + r16*68 + cc;
      float v[8];
#pragma unroll
      for (int k = 0; k < 8; ++k) v[k] = ep[k];
      const int row = bm*128 + wm + i*16 + r16;
      const int colg = bn*128 + wn + cc;
      if constexpr (EPI == EPI_RES) {
        float rv[8];
        ld4(res + (size_t)row * N + colg, rv);
        ld4(res + (size_t)row * N + colg + 4, rv + 4);
#pragma unroll
        for (int k = 0; k < 8; ++k) v[k] += rv[k];
      }
      if constexpr (sizeof(OutT) == 2) {
        union { uint4 q; u16 e[8]; } ov;
#pragma unroll
        for (int k = 0; k < 8; ++k) ov.e[k] = f2b(v[k]);
        *(uint4*)((u16*)C + (size_t)row * N + colg) = ov.q;
      } else {
        float4 o0 = {v[0],v[1],v[2],v[3]}, o1 = {v[4],v[5],v[6],v[7]};
        float* cp = (float*)C + (size_t)row * N + colg;
        *(float4*)cp = o0; *(float4*)(cp + 4) = o1;
      }
    }
  }
}

// ---------------------------------------------------------------------------
// Attention: one block per (window, head).
// ---------------------------------------------------------------------------
__global__ __launch_bounds__(256, 2)
void attn_kernel(const u16* __restrict__ qkv, u16* __restrict__ attn) {
  const int h = blockIdx.x;
  const int n = blockIdx.y;
  const int tid = threadIdx.x;
  const int lane = tid & 63, wv = tid >> 6;
  __shared__ u16 Qs[64*40];
  __shared__ u16 Ks[64*40];
  __shared__ u16 Vt[32*72];
  __shared__ u16 Ps[64*72];
  {
    const int row = tid >> 2, ch = tid & 3;
    const u16* base = qkv + (size_t)(n*64 + row) * 768 + h*32 + ch*8;
    *(uint4*)(Qs + row*40 + ch*8) = *(const uint4*)(base);
    *(uint4*)(Ks + row*40 + ch*8) = *(const uint4*)(base + 256);
    union { uint4 v; u16 e[8]; } tmp;
    tmp.v = *(const uint4*)(base + 512);
#pragma unroll
    for (int j = 0; j < 8; ++j) Vt[(ch*8 + j)*72 + row] = tmp.e[j];
  }
  __syncthreads();
  const int mrow = (wv << 4) + (lane & 15);
  const int q4 = lane >> 4;
  f32x4 s[4];
  {
    bf16x8 qa = *(const bf16x8*)(Qs + mrow*40 + q4*8);
#pragma unroll
    for (int nt = 0; nt < 4; ++nt) {
      bf16x8 kb = *(const bf16x8*)(Ks + (nt*16 + (lane & 15))*40 + q4*8);
      f32x4 z = {0.f, 0.f, 0.f, 0.f};
      s[nt] = __builtin_amdgcn_mfma_f32_16x16x32_bf16(qa, kb, z, 0, 0, 0);
    }
  }
  float pr[4][4];
#pragma unroll
  for (int r = 0; r < 4; ++r) {
    float m0 = fmaxf(fmaxf(s[0][r], s[1][r]), fmaxf(s[2][r], s[3][r]));
    m0 = fmaxf(m0, __shfl_xor(m0, 1, 64));
    m0 = fmaxf(m0, __shfl_xor(m0, 2, 64));
    m0 = fmaxf(m0, __shfl_xor(m0, 4, 64));
    m0 = fmaxf(m0, __shfl_xor(m0, 8, 64));
    const float cs = 0.25500526571944696f;  // log2(e)/sqrt(32)
    float p0 = exp2f(fminf((s[0][r] - m0) * cs, 0.f));
    float p1 = exp2f(fminf((s[1][r] - m0) * cs, 0.f));
    float p2 = exp2f(fminf((s[2][r] - m0) * cs, 0.f));
    float p3 = exp2f(fminf((s[3][r] - m0) * cs, 0.f));
    float sum = p0 + p1 + p2 + p3;
    sum += __shfl_xor(sum, 1, 64);
    sum += __shfl_xor(sum, 2, 64);
    sum += __shfl_xor(sum, 4, 64);
    sum += __shfl_xor(sum, 8, 64);
    const float inv = 1.f / sum;
    pr[0][r] = p0*inv; pr[1][r] = p1*inv; pr[2][r] = p2*inv; pr[3][r] = p3*inv;
  }
  {
    const int c = lane & 15;
#pragma unroll
    for (int nt = 0; nt < 4; ++nt)
#pragma unroll
      for (int r = 0; r < 4; ++r)
        Ps[((wv<<4) + (q4<<2) + r)*72 + nt*16 + c] = f2b(pr[nt][r]);
  }
  __syncthreads();
  f32x4 o0 = {0.f,0.f,0.f,0.f}, o1 = {0.f,0.f,0.f,0.f};
#pragma unroll
  for (int ks = 0; ks < 2; ++ks) {
    bf16x8 pa = *(const bf16x8*)(Ps + mrow*72 + ks*32 + q4*8);
    bf16x8 v0 = *(const bf16x8*)(Vt + (lane & 15)*72 + ks*32 + q4*8);
    bf16x8 v1 = *(const bf16x8*)(Vt + (16 + (lane & 15))*72 + ks*32 + q4*8);
    o0 = __builtin_amdgcn_mfma_f32_16x16x32_bf16(pa, v0, o0, 0, 0, 0);
    o1 = __builtin_amdgcn_mfma_f32_16x16x32_bf16(pa, v1, o1, 0, 0, 0);
  }
  {
    u16* Os = Qs + wv * 640;
    const int c = lane & 15;
#pragma unroll
    for (int r = 0; r < 4; ++r) {
      Os[((q4<<2) + r)*40 + c]      = f2b(o0[r]);
      Os[((q4<<2) + r)*40 + 16 + c] = f2b(o1[r]);
    }
    const int rr = lane >> 2, d0 = (lane & 3) * 8;
    union { uint4 q; u16 e[8]; } ov;
#pragma unroll
    for (int k = 0; k < 8; ++k) ov.e[k] = Os[rr*40 + d0 + k];
    *(uint4*)(attn + (size_t)(n*64 + (wv<<4) + rr) * 256 + h*32 + d0) = ov.q;
  }
}

// ---------------------------------------------------------------------------
// LN2: one wave per token. y (f32|bf16) -> zn bf16.
// ---------------------------------------------------------------------------
template<typename YT>
__global__ __launch_bounds__(256, 4)
void ln2_kernel(const YT* __restrict__ y, const float* __restrict__ g,
                const float* __restrict__ bb, u16* __restrict__ zn) {
  const int t = blockIdx.x * 4 + (threadIdx.x >> 6);
  const int lane = threadIdx.x & 63;
  float f[4];
  ld4(y + (size_t)t*256 + lane*4, f);
  float sum = f[0]+f[1]+f[2]+f[3];
  float sq  = f[0]*f[0]+f[1]*f[1]+f[2]*f[2]+f[3]*f[3];
#pragma unroll
  for (int d = 32; d; d >>= 1) { sum += __shfl_xor(sum, d, 64); sq += __shfl_xor(sq, d, 64); }
  const float mu = sum * (1.f/256.f);
  const float rs = rsqrtf(fmaxf(sq * (1.f/256.f) - mu*mu, 0.f) + 1e-6f);
  const float4 gv = *(const float4*)(g + lane*4);
  const float4 bv = *(const float4*)(bb + lane*4);
  union { ushort4 v; u16 e[4]; } ov;
  ov.e[0] = f2b((f[0]-mu)*rs*gv.x + bv.x);
  ov.e[1] = f2b((f[1]-mu)*rs*gv.y + bv.y);
  ov.e[2] = f2b((f[2]-mu)*rs*gv.z + bv.z);
  ov.e[3] = f2b((f[3]-mu)*rs*gv.w + bv.w);
  *(ushort4*)(zn + (size_t)t*256 + lane*4) = ov.v;
}

// ---------------------------------------------------------------------------
// Scatter: z (token layout, f32) -> out (image layout) with window reverse +
// shift.
// ---------------------------------------------------------------------------
__global__ __launch_bounds__(256, 2)
void scatter_kernel(const float* __restrict__ z, float* __restrict__ out) {
  __shared__ float T[64 * 260];            // T[w][c], pad 260 (float4-aligned)
  const int bx = blockIdx.x;               // b*64 + h
  const int b = bx >> 6, h = bx & 63;
  const int tid = threadIdx.x;
  const int hp = (h + 60) & 63;            // (h-4) mod 64
  const int wi = hp >> 3, tr = hp & 7;
  const int base = (b*64 + wi*8)*64 + tr*8;  // token index at (wj=0, tc=0)
  const int c0 = (tid & 63) * 4;
#pragma unroll
  for (int p = 0; p < 16; ++p) {
    const int r = p*4 + (tid >> 6);        // r = wj*8 + tc, 0..63
    const int t = base + (r >> 3)*64 + (r & 7);
    const float4 v = *(const float4*)(z + (size_t)t*256 + c0);
    *(float4*)(T + ((r + 4) & 63)*260 + c0) = v;   // w_img = (r+4) & 63
  }
  __syncthreads();
  float* ob = out + (size_t)b*1048576 + (size_t)h*64;
#pragma unroll
  for (int p = 0; p < 16; ++p) {
    const int c = p*16 + (tid >> 6)*4 + ((tid & 63) >> 4);
    const int w4 = (tid & 15) * 4;
    float4 v;
    v.x = T[(w4+0)*260 + c];
    v.y = T[(w4+1)*260 + c];
    v.z = T[(w4+2)*260 + c];
    v.w = T[(w4+3)*260 + c];
    *(float4*)(ob + (size_t)c*4096 + w4) = v;
  }
}

// ---------------------------------------------------------------------------
// Workspace layout (nA = 16 Mi elements = 32 MiB bf16 / 64 MiB f32):
//   [0,   2nA)  B   : xn -> attn-out -> zn (bf16)      live until 2nd fc1
//   [2nA, 8nA)  Cb  : qkv (bf16, dead after attn)
//        [2nA, 6nA)  H1 : h1 half (bf16, 64 MiB) overlays Cb head
//        [6nA,10nA)  Z  : z = y+z2 (f32, 64 MiB) overlays Cb tail + A
//   [8nA,10nA)  A   : x_tok (bf16, dead after gemm_proj)
//   [10nA, ..)  D   : y (f32 if yf32 else bf16)
//   then converted weights.
// ---------------------------------------------------------------------------
extern "C" void kernel_launch(void* const* d_in, const int* in_sizes, int n_in,
                              void* d_out, int out_size, void* d_ws, size_t ws_size,
                              hipStream_t stream) {
  const float* x       = (const float*)d_in[0];
  const float* norm1_g = (const float*)d_in[1];
  const float* norm1_b = (const float*)d_in[2];
  const float* in_w    = (const float*)d_in[3];
  const float* in_b    = (const float*)d_in[4];
  const float* out_w   = (const float*)d_in[5];
  const float* out_b   = (const float*)d_in[6];
  const float* proj_w  = (const float*)d_in[7];
  const float* proj_b  = (const float*)d_in[8];
  const float* norm2_g = (const float*)d_in[9];
  const float* norm2_b = (const float*)d_in[10];
  const float* fc1_w   = (const float*)d_in[11];
  const float* fc1_b   = (const float*)d_in[12];
  const float* fc2_w   = (const float*)d_in[13];
  const float* fc2_b   = (const float*)d_in[14];
  float* out = (float*)d_out;

  const size_t nA = 16777216;             // 65536 tokens x 256 ch
  const size_t nH = 8388608;              // tokens*ch per M-half

  char* base = (char*)d_ws;
  const bool yf32 = ws_size >= (14*nA + 1573888 + 1024);

  u16*   B  = (u16*)base;                 // xn -> attn-out -> zn
  u16*   Cb = (u16*)(base + nA*2);        // qkv
  u16*   H1 = (u16*)(base + nA*2);        // h1 half (bf16), overlays Cb
  float* Z  = (float*)(base + nA*6);      // z (f32), overlays Cb tail + A
  u16*   A  = (u16*)(base + nA*8);        // x_tok
  char*  Dp = base + nA*10;               // y
  char*  Wp = Dp + (yf32 ? nA*4 : nA*2);
  u16* W2    = (u16*)Wp;                  // 65536
  u16* inw_h = W2 + 65536;                // 196608
  u16* fc1_h = inw_h + 196608;            // 262144
  u16* fc2_h = fc1_h + 262144;            // 262144
  float* b2v = (float*)(fc2_h + 262144);  // 256

  conv_w<<<768, 256, 0, stream>>>(in_w, inw_h, 196608);
  conv_w<<<1024, 256, 0, stream>>>(fc1_w, fc1_h, 262144);
  conv_w<<<1024, 256, 0, stream>>>(fc2_w, fc2_h, 262144);
  prep_w2<<<256, 256, 0, stream>>>(proj_w, out_w, W2);
  prep_b2<<<1, 256, 0, stream>>>(proj_w, out_b, proj_b, b2v);

  ln1_kernel<<<dim3(128, 16), 256, 0, stream>>>(x, norm1_g, norm1_b, B, A);
  // qkv = xn @ in_w^T + in_b   (65536 x 768 x 256), NB=6
  gemm_bt<768, 256, 6, EPI_BIAS, u16, u16>
      <<<3072, 256, 0, stream>>>(B, inw_h, in_b, nullptr, Cb);
  attn_kernel<<<dim3(8, 1024), 256, 0, stream>>>(Cb, B);
  if (yf32) {
    float* D = (float*)Dp;
    gemm_bt<256, 256, 2, EPI_RES, float, u16>
        <<<1024, 256, 0, stream>>>(B, W2, b2v, A, D);
    ln2_kernel<float><<<16384, 256, 0, stream>>>(D, norm2_g, norm2_b, B);
    for (int mh = 0; mh < 2; ++mh) {
      // h1 = gelu(zn @ fc1^T + b1)   (32768 x 1024 x 256), NB=8
      gemm_bt<1024, 256, 8, EPI_GELU, u16, u16>
          <<<2048, 256, 0, stream>>>(B + mh*nH, fc1_h, fc1_b, nullptr, H1);
      // z = y + h1 @ fc2^T + b2      (32768 x 256 x 1024), NB=2
      gemm_bt<256, 1024, 2, EPI_RES, float, float>
          <<<512, 256, 0, stream>>>(H1, fc2_h, fc2_b, D + mh*nH, Z + mh*nH);
    }
  } else {
    u16* D = (u16*)Dp;
    gemm_bt<256, 256, 2, EPI_RES, u16, u16>
        <<<1024, 256, 0, stream>>>(B, W2, b2v, A, D);
    ln2_kernel<u16><<<16384, 256, 0, stream>>>(D, norm2_g, norm2_b, B);
    for (int mh = 0; mh < 2; ++mh) {
      gemm_bt<1024, 256, 8, EPI_GELU, u16, u16>
          <<<2048, 256, 0, stream>>>(B + mh*nH, fc1_h, fc1_b, nullptr, H1);
      gemm_bt<256, 1024, 2, EPI_RES, float, u16>
          <<<512, 256, 0, stream>>>(H1, fc2_h, fc2_b, (u16*)Dp + mh*nH, Z + mh*nH);
    }
  }
  scatter_kernel<<<1024, 256, 0, stream>>>(Z, out);
}

// Round 6
// 432.446 us; speedup vs baseline: 1.8650x; 1.0629x over previous
//
#include <hip/hip_runtime.h>

typedef unsigned short u16;
typedef unsigned int   u32;
typedef __bf16 bf16_t;
typedef bf16_t bf16x8 __attribute__((ext_vector_type(8)));
typedef float  f32x4  __attribute__((ext_vector_type(4)));

__device__ __forceinline__ float b2f(u16 u) {
  union { float f; u32 i; } v; v.i = ((u32)u) << 16; return v.f;
}
__device__ __forceinline__ u16 f2b(float f) {
  union { float f; u32 i; } v; v.f = f;
  u32 r = v.i + 0x7FFFu + ((v.i >> 16) & 1u);
  return (u16)(r >> 16);
}
__device__ __forceinline__ void ld4(const float* p, float* o) {
  const float4 v = *(const float4*)p; o[0]=v.x; o[1]=v.y; o[2]=v.z; o[3]=v.w;
}
__device__ __forceinline__ void ld4(const u16* p, float* o) {
  union { ushort4 v; u16 e[4]; } u; u.v = *(const ushort4*)p;
#pragma unroll
  for (int k = 0; k < 4; ++k) o[k] = b2f(u.e[k]);
}

// async global->LDS DMA, 16B per lane. LDS dest is wave-uniform base +
// lane*16; global src is per-lane.
__device__ __forceinline__ void gld16(const u16* g, u16* l) {
  __builtin_amdgcn_global_load_lds(
      (const __attribute__((address_space(1))) void*)g,
      (__attribute__((address_space(3))) void*)l, 16, 0, 0);
}

// gelu(v) = 0.5 v (1 + erf(v/sqrt(2))), erf via Abramowitz-Stegun 7.1.26
// (|err| <= 1.5e-7, far below bf16 quantization of h1).
__device__ __forceinline__ float fast_gelu(float v) {
  const float u = v * 0.7071067811865475f;
  const float s = fabsf(u);
  const float t = __builtin_amdgcn_rcpf(fmaf(0.3275911f, s, 1.f));
  const float poly = t*(0.254829592f + t*(-0.284496736f +
                     t*(1.421413741f + t*(-1.453152027f + t*1.061405429f))));
  const float E = exp2f(-s*s*1.4426950408889634f);
  const float q = poly * E;                   // = 1 - erf(s)
  const float phi = (u >= 0.f) ? (2.f - q) : q;  // 1 + erf(u)
  return 0.5f * v * phi;
}

// ---------------------------------------------------------------------------
// Prep kernels
// ---------------------------------------------------------------------------
__global__ void conv_w(const float* __restrict__ src, u16* __restrict__ dst, int n) {
  const int i = blockIdx.x * 256 + threadIdx.x;
  if (i < n) dst[i] = f2b(src[i]);
}

__global__ void prep_w2(const float* __restrict__ proj_w, const float* __restrict__ out_w,
                        u16* __restrict__ W2) {
  const int o = blockIdx.x, c = threadIdx.x;
  float acc = 0.f;
  for (int m = 0; m < 256; ++m)
    acc += proj_w[o*256 + m] * out_w[m*256 + c];
  W2[o*256 + c] = f2b(acc);
}

__global__ void prep_b2(const float* __restrict__ proj_w, const float* __restrict__ out_b,
                        const float* __restrict__ proj_b, float* __restrict__ b2v) {
  const int o = threadIdx.x;
  float acc = proj_b[o];
  for (int m = 0; m < 256; ++m) acc += proj_w[o*256 + m] * out_b[m];
  b2v[o] = acc;
}

// ---------------------------------------------------------------------------
// LN1 over C + shifted window partition.
// ---------------------------------------------------------------------------
__global__ __launch_bounds__(256, 2)
void ln1_kernel(const float* __restrict__ x, const float* __restrict__ g,
                const float* __restrict__ bb, u16* __restrict__ xn_tok,
                u16* __restrict__ x_tok) {
  const int bx = blockIdx.x;                 // 128: h*2 + half
  const int h = bx >> 1, w0 = (bx & 1) << 5;
  const int b = blockIdx.y;
  const int tid = threadIdx.x;
  __shared__ float X[256][33];
  __shared__ float ps[8][32], pq[8][32];
  __shared__ float mu_s[32], rs_s[32];
  const int w = tid & 31, cg = tid >> 5;
  float sum = 0.f, sq = 0.f;
  const float* xb = x + ((size_t)b * 256) * 4096 + h * 64 + w0;
  for (int i = 0; i < 32; ++i) {
    const int c = i*8 + cg;
    const float v = xb[(size_t)c * 4096 + w];
    X[c][w] = v; sum += v; sq += v*v;
  }
  ps[cg][w] = sum; pq[cg][w] = sq;
  __syncthreads();
  if (tid < 32) {
    float s = 0.f, q2 = 0.f;
#pragma unroll
    for (int j = 0; j < 8; ++j) { s += ps[j][tid]; q2 += pq[j][tid]; }
    const float mu = s * (1.f/256.f);
    mu_s[tid] = mu;
    rs_s[tid] = rsqrtf(fmaxf(q2 * (1.f/256.f) - mu*mu, 0.f) + 1e-6f);
  }
  __syncthreads();
  const int c = tid;
  const float gc = g[c], bc = bb[c];
  const int hp = (h + 60) & 63;              // h' = (h-4) mod 64
  const int wi = hp >> 3, tr = hp & 7;
  const int tokb = (b << 6) + (wi << 3);
  for (int w2 = 0; w2 < 32; ++w2) {
    const int wp = (w0 + w2 + 60) & 63;
    const int tok = (tokb + (wp >> 3)) * 64 + tr*8 + (wp & 7);
    const float v = X[c][w2];
    xn_tok[(size_t)tok * 256 + c] = f2b((v - mu_s[w2]) * rs_s[w2] * gc + bc);
    x_tok [(size_t)tok * 256 + c] = f2b(v);
  }
}

// ---------------------------------------------------------------------------
// MFMA GEMM: C = epi(A @ W^T + bias [+ res]).
// 128x128 tile, BK=64, SINGLE 32KB LDS buffer (m97 structure): stage via
// global_load_lds w/ pre-swizzled per-lane source -> drain barrier ->
// compute -> WAR barrier. Latency hidden by inter-block interleave
// (32KB LDS -> 5 blocks/CU), not intra-block dbuf (the pre-barrier
// vmcnt(0) drain defeats dbuf overlap; round-5 counters: 50% idle at
// 2 blocks/CU).
// ---------------------------------------------------------------------------
constexpr int EPI_BIAS = 0, EPI_GELU = 1, EPI_RES = 2;

template<int N, int K, int NB, int EPI, typename OutT, typename ResT>
__global__ __launch_bounds__(256, 2)
void gemm_bt(const u16* __restrict__ A, const u16* __restrict__ W,
             const float* __restrict__ bias, const ResT* __restrict__ res,
             OutT* __restrict__ C) {
  __shared__ u16 SMEM[2*128*64];           // 32 KB: A 16K | W 16K
  u16* As = SMEM;
  u16* Ws = SMEM + 8192;
  const int tid = threadIdx.x;
  const int lane = tid & 63;
  const int wave = tid >> 6;
  const int wm = (wave >> 1) << 6;
  const int wn = (wave & 1) << 6;
  const int id = blockIdx.x;
  const int kk = id >> 3, xx = id & 7;
  const int bn = kk % NB;
  const int bm = (kk / NB) * 8 + xx;
  const u16* Ab = A + (size_t)bm * 128 * K;
  const u16* Wb = W + (size_t)bn * 128 * K;
  f32x4 acc[4][4] = {};

  // staging geometry: per wave 4 issues x 1KB; lane l covers LDS elements
  // (wave*4+e)*512 + l*8 = row r=(wave*4+e)*8 + l/8, slot p=l&7.
  // source col chunk = p ^ (r&7)  (so LDS[r][p] = G[r][p^(r&7)]).
  const int srl = lane >> 3;               // row-within-8
  const int sp  = lane & 7;                // slot
  auto stage = [&](int kb) {
#pragma unroll
    for (int e = 0; e < 4; ++e) {
      const int r = (wave*4 + e)*8 + srl;
      const int c = sp ^ (r & 7);
      const int lo = (wave*4 + e)*512;
      gld16(Ab + (size_t)r*K + kb + c*8, As + lo);
      gld16(Wb + (size_t)r*K + kb + c*8, Ws + lo);
    }
  };

  for (int kc = 0; kc < K/64; ++kc) {
    stage(kc*64);
    __syncthreads();                       // vmcnt(0) drain -> tile ready
#pragma unroll
    for (int ks = 0; ks < 2; ++ks) {
      bf16x8 af[4], wf[4];
#pragma unroll
      for (int i = 0; i < 4; ++i) {
        const int ra = wm + i*16 + (lane & 15);
        const int pa = ((ks<<2) + (lane >> 4)) ^ (ra & 7);
        af[i] = *(const bf16x8*)(As + ra*64 + pa*8);
        const int rb = wn + i*16 + (lane & 15);
        const int pb = ((ks<<2) + (lane >> 4)) ^ (rb & 7);
        wf[i] = *(const bf16x8*)(Ws + rb*64 + pb*8);
      }
#pragma unroll
      for (int i = 0; i < 4; ++i)
#pragma unroll
        for (int j = 0; j < 4; ++j)
          acc[i][j] = __builtin_amdgcn_mfma_f32_16x16x32_bf16(af[i], wf[j], acc[i][j], 0, 0, 0);
    }
    __syncthreads();                       // WAR guard (also pre-epilogue)
  }
  float* Es = (float*)SMEM + wave * (16*68);
  const int c0 = lane & 15, g4 = lane >> 4;
  float bj[4];
#pragma unroll
  for (int j = 0; j < 4; ++j) bj[j] = bias[bn*128 + wn + j*16 + c0];
#pragma unroll
  for (int i = 0; i < 4; ++i) {
#pragma unroll
    for (int j = 0; j < 4; ++j)
#pragma unroll
      for (int r = 0; r < 4; ++r) {
        float v = acc[i][j][r] + bj[j];
        if constexpr (EPI == EPI_GELU) v = fast_gelu(v);
        Es[(g4*4 + r)*68 + j*16 + c0] = v;
      }
#pragma unroll
    for (int t = 0; t < 2; ++t) {
      const int r16 = t*8 + (lane >> 3);
      const int cc = (lane & 7) * 8;
      const float* ep = Es + r16*68 + cc;
      float v[8];
#pragma unroll
      for (int k = 0; k < 8; ++k) v[k] = ep[k];
      const int row = bm*128 + wm + i*16 + r16;
      const int colg = bn*128 + wn + cc;
      if constexpr (EPI == EPI_RES) {
        float rv[8];
        ld4(res + (size_t)row * N + colg, rv);
        ld4(res + (size_t)row * N + colg + 4, rv + 4);
#pragma unroll
        for (int k = 0; k < 8; ++k) v[k] += rv[k];
      }
      if constexpr (sizeof(OutT) == 2) {
        union { uint4 q; u16 e[8]; } ov;
#pragma unroll
        for (int k = 0; k < 8; ++k) ov.e[k] = f2b(v[k]);
        *(uint4*)((u16*)C + (size_t)row * N + colg) = ov.q;
      } else {
        float4 o0 = {v[0],v[1],v[2],v[3]}, o1 = {v[4],v[5],v[6],v[7]};
        float* cp = (float*)C + (size_t)row * N + colg;
        *(float4*)cp = o0; *(float4*)(cp + 4) = o1;
      }
    }
  }
}

// ---------------------------------------------------------------------------
// Attention: one block per (window, head).
// ---------------------------------------------------------------------------
__global__ __launch_bounds__(256, 2)
void attn_kernel(const u16* __restrict__ qkv, u16* __restrict__ attn) {
  const int h = blockIdx.x;
  const int n = blockIdx.y;
  const int tid = threadIdx.x;
  const int lane = tid & 63, wv = tid >> 6;
  __shared__ u16 Qs[64*40];
  __shared__ u16 Ks[64*40];
  __shared__ u16 Vt[32*72];
  __shared__ u16 Ps[64*72];
  {
    const int row = tid >> 2, ch = tid & 3;
    const u16* base = qkv + (size_t)(n*64 + row) * 768 + h*32 + ch*8;
    *(uint4*)(Qs + row*40 + ch*8) = *(const uint4*)(base);
    *(uint4*)(Ks + row*40 + ch*8) = *(const uint4*)(base + 256);
    union { uint4 v; u16 e[8]; } tmp;
    tmp.v = *(const uint4*)(base + 512);
#pragma unroll
    for (int j = 0; j < 8; ++j) Vt[(ch*8 + j)*72 + row] = tmp.e[j];
  }
  __syncthreads();
  const int mrow = (wv << 4) + (lane & 15);
  const int q4 = lane >> 4;
  f32x4 s[4];
  {
    bf16x8 qa = *(const bf16x8*)(Qs + mrow*40 + q4*8);
#pragma unroll
    for (int nt = 0; nt < 4; ++nt) {
      bf16x8 kb = *(const bf16x8*)(Ks + (nt*16 + (lane & 15))*40 + q4*8);
      f32x4 z = {0.f, 0.f, 0.f, 0.f};
      s[nt] = __builtin_amdgcn_mfma_f32_16x16x32_bf16(qa, kb, z, 0, 0, 0);
    }
  }
  float pr[4][4];
#pragma unroll
  for (int r = 0; r < 4; ++r) {
    float m0 = fmaxf(fmaxf(s[0][r], s[1][r]), fmaxf(s[2][r], s[3][r]));
    m0 = fmaxf(m0, __shfl_xor(m0, 1, 64));
    m0 = fmaxf(m0, __shfl_xor(m0, 2, 64));
    m0 = fmaxf(m0, __shfl_xor(m0, 4, 64));
    m0 = fmaxf(m0, __shfl_xor(m0, 8, 64));
    const float cs = 0.25500526571944696f;  // log2(e)/sqrt(32)
    float p0 = exp2f(fminf((s[0][r] - m0) * cs, 0.f));
    float p1 = exp2f(fminf((s[1][r] - m0) * cs, 0.f));
    float p2 = exp2f(fminf((s[2][r] - m0) * cs, 0.f));
    float p3 = exp2f(fminf((s[3][r] - m0) * cs, 0.f));
    float sum = p0 + p1 + p2 + p3;
    sum += __shfl_xor(sum, 1, 64);
    sum += __shfl_xor(sum, 2, 64);
    sum += __shfl_xor(sum, 4, 64);
    sum += __shfl_xor(sum, 8, 64);
    const float inv = 1.f / sum;
    pr[0][r] = p0*inv; pr[1][r] = p1*inv; pr[2][r] = p2*inv; pr[3][r] = p3*inv;
  }
  {
    const int c = lane & 15;
#pragma unroll
    for (int nt = 0; nt < 4; ++nt)
#pragma unroll
      for (int r = 0; r < 4; ++r)
        Ps[((wv<<4) + (q4<<2) + r)*72 + nt*16 + c] = f2b(pr[nt][r]);
  }
  __syncthreads();
  f32x4 o0 = {0.f,0.f,0.f,0.f}, o1 = {0.f,0.f,0.f,0.f};
#pragma unroll
  for (int ks = 0; ks < 2; ++ks) {
    bf16x8 pa = *(const bf16x8*)(Ps + mrow*72 + ks*32 + q4*8);
    bf16x8 v0 = *(const bf16x8*)(Vt + (lane & 15)*72 + ks*32 + q4*8);
    bf16x8 v1 = *(const bf16x8*)(Vt + (16 + (lane & 15))*72 + ks*32 + q4*8);
    o0 = __builtin_amdgcn_mfma_f32_16x16x32_bf16(pa, v0, o0, 0, 0, 0);
    o1 = __builtin_amdgcn_mfma_f32_16x16x32_bf16(pa, v1, o1, 0, 0, 0);
  }
  {
    u16* Os = Qs + wv * 640;
    const int c = lane & 15;
#pragma unroll
    for (int r = 0; r < 4; ++r) {
      Os[((q4<<2) + r)*40 + c]      = f2b(o0[r]);
      Os[((q4<<2) + r)*40 + 16 + c] = f2b(o1[r]);
    }
    const int rr = lane >> 2, d0 = (lane & 3) * 8;
    union { uint4 q; u16 e[8]; } ov;
#pragma unroll
    for (int k = 0; k < 8; ++k) ov.e[k] = Os[rr*40 + d0 + k];
    *(uint4*)(attn + (size_t)(n*64 + (wv<<4) + rr) * 256 + h*32 + d0) = ov.q;
  }
}

// ---------------------------------------------------------------------------
// LN2: one wave per token. y (f32|bf16) -> zn bf16.
// ---------------------------------------------------------------------------
template<typename YT>
__global__ __launch_bounds__(256, 4)
void ln2_kernel(const YT* __restrict__ y, const float* __restrict__ g,
                const float* __restrict__ bb, u16* __restrict__ zn) {
  const int t = blockIdx.x * 4 + (threadIdx.x >> 6);
  const int lane = threadIdx.x & 63;
  float f[4];
  ld4(y + (size_t)t*256 + lane*4, f);
  float sum = f[0]+f[1]+f[2]+f[3];
  float sq  = f[0]*f[0]+f[1]*f[1]+f[2]*f[2]+f[3]*f[3];
#pragma unroll
  for (int d = 32; d; d >>= 1) { sum += __shfl_xor(sum, d, 64); sq += __shfl_xor(sq, d, 64); }
  const float mu = sum * (1.f/256.f);
  const float rs = rsqrtf(fmaxf(sq * (1.f/256.f) - mu*mu, 0.f) + 1e-6f);
  const float4 gv = *(const float4*)(g + lane*4);
  const float4 bv = *(const float4*)(bb + lane*4);
  union { ushort4 v; u16 e[4]; } ov;
  ov.e[0] = f2b((f[0]-mu)*rs*gv.x + bv.x);
  ov.e[1] = f2b((f[1]-mu)*rs*gv.y + bv.y);
  ov.e[2] = f2b((f[2]-mu)*rs*gv.z + bv.z);
  ov.e[3] = f2b((f[3]-mu)*rs*gv.w + bv.w);
  *(ushort4*)(zn + (size_t)t*256 + lane*4) = ov.v;
}

// ---------------------------------------------------------------------------
// Scatter: z (token layout, f32) -> out (image layout) with window reverse +
// shift.
// ---------------------------------------------------------------------------
__global__ __launch_bounds__(256, 2)
void scatter_kernel(const float* __restrict__ z, float* __restrict__ out) {
  __shared__ float T[64 * 260];            // T[w][c], pad 260 (float4-aligned)
  const int bx = blockIdx.x;               // b*64 + h
  const int b = bx >> 6, h = bx & 63;
  const int tid = threadIdx.x;
  const int hp = (h + 60) & 63;            // (h-4) mod 64
  const int wi = hp >> 3, tr = hp & 7;
  const int base = (b*64 + wi*8)*64 + tr*8;  // token index at (wj=0, tc=0)
  const int c0 = (tid & 63) * 4;
#pragma unroll
  for (int p = 0; p < 16; ++p) {
    const int r = p*4 + (tid >> 6);        // r = wj*8 + tc, 0..63
    const int t = base + (r >> 3)*64 + (r & 7);
    const float4 v = *(const float4*)(z + (size_t)t*256 + c0);
    *(float4*)(T + ((r + 4) & 63)*260 + c0) = v;   // w_img = (r+4) & 63
  }
  __syncthreads();
  float* ob = out + (size_t)b*1048576 + (size_t)h*64;
#pragma unroll
  for (int p = 0; p < 16; ++p) {
    const int c = p*16 + (tid >> 6)*4 + ((tid & 63) >> 4);
    const int w4 = (tid & 15) * 4;
    float4 v;
    v.x = T[(w4+0)*260 + c];
    v.y = T[(w4+1)*260 + c];
    v.z = T[(w4+2)*260 + c];
    v.w = T[(w4+3)*260 + c];
    *(float4*)(ob + (size_t)c*4096 + w4) = v;
  }
}

// ---------------------------------------------------------------------------
// Workspace layout (nA = 16 Mi elements = 32 MiB bf16 / 64 MiB f32):
//   [0,   2nA)  B   : xn -> attn-out -> zn (bf16)      live until 2nd fc1
//   [2nA, 8nA)  Cb  : qkv (bf16, dead after attn)
//        [2nA, 6nA)  H1 : h1 half (bf16, 64 MiB) overlays Cb head
//        [6nA,10nA)  Z  : z = y+z2 (f32, 64 MiB) overlays Cb tail + A
//   [8nA,10nA)  A   : x_tok (bf16, dead after gemm_proj)
//   [10nA, ..)  D   : y (f32 if yf32 else bf16)
//   then converted weights.
// ---------------------------------------------------------------------------
extern "C" void kernel_launch(void* const* d_in, const int* in_sizes, int n_in,
                              void* d_out, int out_size, void* d_ws, size_t ws_size,
                              hipStream_t stream) {
  const float* x       = (const float*)d_in[0];
  const float* norm1_g = (const float*)d_in[1];
  const float* norm1_b = (const float*)d_in[2];
  const float* in_w    = (const float*)d_in[3];
  const float* in_b    = (const float*)d_in[4];
  const float* out_w   = (const float*)d_in[5];
  const float* out_b   = (const float*)d_in[6];
  const float* proj_w  = (const float*)d_in[7];
  const float* proj_b  = (const float*)d_in[8];
  const float* norm2_g = (const float*)d_in[9];
  const float* norm2_b = (const float*)d_in[10];
  const float* fc1_w   = (const float*)d_in[11];
  const float* fc1_b   = (const float*)d_in[12];
  const float* fc2_w   = (const float*)d_in[13];
  const float* fc2_b   = (const float*)d_in[14];
  float* out = (float*)d_out;

  const size_t nA = 16777216;             // 65536 tokens x 256 ch
  const size_t nH = 8388608;              // tokens*ch per M-half

  char* base = (char*)d_ws;
  const bool yf32 = ws_size >= (14*nA + 1573888 + 1024);

  u16*   B  = (u16*)base;                 // xn -> attn-out -> zn
  u16*   Cb = (u16*)(base + nA*2);        // qkv
  u16*   H1 = (u16*)(base + nA*2);        // h1 half (bf16), overlays Cb
  float* Z  = (float*)(base + nA*6);      // z (f32), overlays Cb tail + A
  u16*   A  = (u16*)(base + nA*8);        // x_tok
  char*  Dp = base + nA*10;               // y
  char*  Wp = Dp + (yf32 ? nA*4 : nA*2);
  u16* W2    = (u16*)Wp;                  // 65536
  u16* inw_h = W2 + 65536;                // 196608
  u16* fc1_h = inw_h + 196608;            // 262144
  u16* fc2_h = fc1_h + 262144;            // 262144
  float* b2v = (float*)(fc2_h + 262144);  // 256

  conv_w<<<768, 256, 0, stream>>>(in_w, inw_h, 196608);
  conv_w<<<1024, 256, 0, stream>>>(fc1_w, fc1_h, 262144);
  conv_w<<<1024, 256, 0, stream>>>(fc2_w, fc2_h, 262144);
  prep_w2<<<256, 256, 0, stream>>>(proj_w, out_w, W2);
  prep_b2<<<1, 256, 0, stream>>>(proj_w, out_b, proj_b, b2v);

  ln1_kernel<<<dim3(128, 16), 256, 0, stream>>>(x, norm1_g, norm1_b, B, A);
  // qkv = xn @ in_w^T + in_b   (65536 x 768 x 256), NB=6
  gemm_bt<768, 256, 6, EPI_BIAS, u16, u16>
      <<<3072, 256, 0, stream>>>(B, inw_h, in_b, nullptr, Cb);
  attn_kernel<<<dim3(8, 1024), 256, 0, stream>>>(Cb, B);
  if (yf32) {
    float* D = (float*)Dp;
    gemm_bt<256, 256, 2, EPI_RES, float, u16>
        <<<1024, 256, 0, stream>>>(B, W2, b2v, A, D);
    ln2_kernel<float><<<16384, 256, 0, stream>>>(D, norm2_g, norm2_b, B);
    for (int mh = 0; mh < 2; ++mh) {
      // h1 = gelu(zn @ fc1^T + b1)   (32768 x 1024 x 256), NB=8
      gemm_bt<1024, 256, 8, EPI_GELU, u16, u16>
          <<<2048, 256, 0, stream>>>(B + mh*nH, fc1_h, fc1_b, nullptr, H1);
      // z = y + h1 @ fc2^T + b2      (32768 x 256 x 1024), NB=2
      gemm_bt<256, 1024, 2, EPI_RES, float, float>
          <<<512, 256, 0, stream>>>(H1, fc2_h, fc2_b, D + mh*nH, Z + mh*nH);
    }
  } else {
    u16* D = (u16*)Dp;
    gemm_bt<256, 256, 2, EPI_RES, u16, u16>
        <<<1024, 256, 0, stream>>>(B, W2, b2v, A, D);
    ln2_kernel<u16><<<16384, 256, 0, stream>>>(D, norm2_g, norm2_b, B);
    for (int mh = 0; mh < 2; ++mh) {
      gemm_bt<1024, 256, 8, EPI_GELU, u16, u16>
          <<<2048, 256, 0, stream>>>(B + mh*nH, fc1_h, fc1_b, nullptr, H1);
      gemm_bt<256, 1024, 2, EPI_RES, float, u16>
          <<<512, 256, 0, stream>>>(H1, fc2_h, fc2_b, (u16*)Dp + mh*nH, Z + mh*nH);
    }
  }
  scatter_kernel<<<1024, 256, 0, stream>>>(Z, out);
}